// Round 12
// baseline (128.882 us; speedup 1.0000x reference)
//
#include <hip/hip_runtime.h>
#include <math.h>

#define NA   21504   // 128^2 + 64^2 + 32^2
#define NA0  16384
#define NA01 20480
#define NG   100
#define NB   16
#define NC   10      // N_CAND
#define NCHK 84      // 256-anchor chunks per image
#define NBLK 1344    // NCHK * NB
#define MAXC 192     // candidate cap (true max in_both = 75)
#define MCAP 1024    // matched-anchor list capacity (true max = 100*10)
#define MSTRIDE 64   // ints between mcount[b] entries (256B: one line each)
#define DSTRIDE 64   // ints between doneA[b] entries

__device__ __forceinline__ float softplusf(float x) {
    return fmaxf(x, 0.f) + log1pf(expf(-fabsf(x)));
}

// monotone float->u32 mapping: a<b  <=>  map(a)<map(b)
__device__ __forceinline__ unsigned int fmono(float f) {
    unsigned int u = __float_as_uint(f);
    return (f < 0.f) ? ~u : (u | 0x80000000u);
}

// ---------------- decode + in-block raster + chunked compaction ----------------
// A0/OC written ONLY for fg anchors (all downstream consumers are fg-only).
__global__ __launch_bounds__(256) void k_decode(
    const float* __restrict__ reg0, const float* __restrict__ obj0,
    const float* __restrict__ reg1, const float* __restrict__ obj1,
    const float* __restrict__ reg2, const float* __restrict__ obj2,
    const float* __restrict__ labels,
    float4* __restrict__ A0, float* __restrict__ OC,
    int* __restrict__ cidx, int* __restrict__ bcnt,
    float* __restrict__ pSp)
{
    int b  = blockIdx.y;
    int bx = blockIdx.x;
    int tid = threadIdx.x;
    int a = bx * 256 + tid;

    int W, ry0, rows; float s;
    if (bx < 64)      { W = 128; s = 8.f;  ry0 = bx * 2;        rows = 2; }
    else if (bx < 80) { W = 64;  s = 16.f; ry0 = (bx - 64) * 4; rows = 4; }
    else              { W = 32;  s = 32.f; ry0 = (bx - 80) * 8; rows = 8; }

    __shared__ unsigned int smask[8];
    if (tid < 8) smask[tid] = 0u;
    __syncthreads();

    // raster: thread g<100 rasterizes GT g's (box ∪ center) rect ∩ this block's rows
    if (tid < NG) {
        const float* L = labels + (b * NG + tid) * 5;
        float gx = L[1], gy = L[2], gw = L[3], gh = L[4];
        float r = 2.5f * s;
        float tlx = gx - 0.5f * gw, tly = gy - 0.5f * gh;
        float brx = gx + 0.5f * gw, bry = gy + 0.5f * gh;
        float cxl = gx - r, cxh = gx + r, cyl = gy - r, cyh = gy + r;
        float lox = fminf(tlx, cxl), hix = fmaxf(brx, cxh);
        float loy = fminf(tly, cyl), hiy = fmaxf(bry, cyh);
        int ixA = (int)floorf(lox / s - 0.5f) - 1;
        int ixB = (int)ceilf (hix / s - 0.5f) + 1;
        int iyA = (int)floorf(loy / s - 0.5f) - 1;
        int iyB = (int)ceilf (hiy / s - 0.5f) + 1;
        ixA = max(ixA, 0); ixB = min(ixB, W - 1);
        iyA = max(iyA, ry0); iyB = min(iyB, ry0 + rows - 1);
        for (int iy = iyA; iy <= iyB; iy++) {
            float yc = ((float)iy + 0.5f) * s;
            float mb = fminf(yc - tly, bry - yc);
            float mc = fminf(yc - cyl, cyh - yc);
            for (int ix = ixA; ix <= ixB; ix++) {
                float xc = ((float)ix + 0.5f) * s;
                bool inb = fminf(fminf(xc - tlx, brx - xc), mb) > 0.f;
                bool inc = fminf(fminf(xc - cxl, cxh - xc), mc) > 0.f;
                if (inb || inc) {
                    int bit = (iy - ry0) * W + ix;
                    atomicOr(&smask[bit >> 5], 1u << (bit & 31));
                }
            }
        }
    }

    int x, y, hw, loc;
    const float* regp; const float* objp;
    if (a < NA0)       { x = a & 127;           y = a >> 7; hw = 16384; loc = y * 128 + x; regp = reg0; objp = obj0; }
    else if (a < NA01) { int i = a - NA0;  x = i & 63; y = i >> 6; hw = 4096;  loc = y * 64 + x;  regp = reg1; objp = obj1; }
    else               { int i = a - NA01; x = i & 31; y = i >> 5; hw = 1024;  loc = y * 32 + x;  regp = reg2; objp = obj2; }

    float r0 = regp[(b * 4 + 0) * hw + loc];
    float r1 = regp[(b * 4 + 1) * hw + loc];
    float r2 = regp[(b * 4 + 2) * hw + loc];
    float r3 = regp[(b * 4 + 3) * hw + loc];
    float ol = objp[b * hw + loc];

    float px = (r0 + (float)x) * s, py = (r1 + (float)y) * s;
    float pw = expf(r2) * s,        ph = expf(r3) * s;
    float ocv = softplusf(-ol);

    __syncthreads();                      // raster bitmap complete
    bool fga = (smask[tid >> 5] >> (tid & 31)) & 1u;

    int idx = b * NA + a;
    if (fga) {
        A0[idx] = make_float4(px - 0.5f * pw, py - 0.5f * ph, px + 0.5f * pw, py + 0.5f * ph);
        OC[idx] = ocv;
    }

    // per-block partial of softplus(ol) = OC + ol  (exact)
    float sp = ocv + ol;
    for (int off = 32; off > 0; off >>= 1) sp += __shfl_down(sp, off);

    unsigned long long mask = __ballot(fga);
    int lane = tid & 63, wid = tid >> 6;
    __shared__ float wSp[4];
    __shared__ int   wcnt[4];
    if (lane == 0) { wSp[wid] = sp; wcnt[wid] = __popcll(mask); }
    __syncthreads();
    int wbase = 0;
    #pragma unroll
    for (int w2 = 0; w2 < 4; w2++) if (w2 < wid) wbase += wcnt[w2];
    if (fga) {
        int prefix = __popcll(mask & ((1ull << lane) - 1ull));
        cidx[b * NA + bx * 256 + wbase + prefix] = a;
    }
    if (tid == 0) {
        bcnt[b * NCHK + bx] = wcnt[0] + wcnt[1] + wcnt[2] + wcnt[3];
        pSp[b * NCHK + bx]  = wSp[0] + wSp[1] + wSp[2] + wSp[3];
    }
}

// ---------------- pack into dense arrays + init match scratch (fg-only) ----------------
__global__ __launch_bounds__(256) void k_pack(
    const float4* __restrict__ A0, const float* __restrict__ OC,
    const int* __restrict__ cidx, const int* __restrict__ bcnt,
    float4* __restrict__ PK0, float* __restrict__ PKO, int* __restrict__ PKA,
    int* __restrict__ fcnt,
    int* __restrict__ n_match, int* __restrict__ mg_min,
    unsigned long long* __restrict__ bestkey,
    int* __restrict__ mcount, int* __restrict__ fbflag)
{
    int b = blockIdx.y, bx = blockIdx.x, tid = threadIdx.x;
    int v = 0;
    for (int i = tid; i < bx; i += 256) v += bcnt[b * NCHK + i];
    for (int off = 32; off > 0; off >>= 1) v += __shfl_down(v, off);
    __shared__ int ws[4];
    int wid = tid >> 6;
    if ((tid & 63) == 0) ws[wid] = v;
    __syncthreads();
    int base = ws[0] + ws[1] + ws[2] + ws[3];
    int nt = bcnt[b * NCHK + bx];
    if (tid < nt) {
        int a = cidx[b * NA + bx * 256 + tid];
        int idx = b * NA + a;
        int d = b * NA + base + tid;
        PK0[d] = A0[idx];
        PKO[d] = OC[idx];
        PKA[d] = a;
        n_match[idx] = 0;
        mg_min[idx]  = 0x7fffffff;
        bestkey[idx] = 0xFFFFFFFFFFFFFFFFull;
    }
    if (bx == NCHK - 1 && tid == 0) fcnt[b] = base + nt;
    if (bx == 0 && tid == 0) { mcount[b * MSTRIDE] = 0; fbflag[b] = 0; }
}

// ---------------- assignment + folded sparse loss + folded finalize ----------------
__global__ __launch_bounds__(256) void k_assign(
    const float* __restrict__ labels, const float4* __restrict__ A0,
    const float* __restrict__ OC,
    const float* __restrict__ obj0, const float* __restrict__ obj1,
    const float* __restrict__ obj2,
    const float4* __restrict__ PK0, const float* __restrict__ PKO,
    const int* __restrict__ PKA, const int* __restrict__ fcnt,
    int* __restrict__ n_match, int* __restrict__ mg_min,
    int* __restrict__ mlist, int* __restrict__ mcount,
    unsigned long long* __restrict__ bestkey, int* __restrict__ fbflag,
    const float* __restrict__ pSp,
    float* __restrict__ pIl2, float* __restrict__ pOl, int* __restrict__ pNf2,
    int* __restrict__ doneA, int* __restrict__ gdone,
    float* __restrict__ out)
{
    int blk = blockIdx.x;
    int b = blk / NG, g = blk % NG;
    int tid = threadIdx.x;

    __shared__ float sio[256 * NC];
    __shared__ int   si2[256 * NC];
    __shared__ int   cand_a[MAXC];
    __shared__ float cand_c[MAXC];
    __shared__ int   scnt;
    __shared__ int   s_t, s_g;

    const float* L = labels + (b * NG + g) * 5;
    float l0 = L[0], gx = L[1], gy = L[2], gw = L[3], gh = L[4];
    bool gv = (l0 + gx + gy + gw + gh) > 0.f;
    int bbase = b * NA;

    if (gv) {
        float g_tlx = gx - 0.5f * gw, g_tly = gy - 0.5f * gh;
        float g_brx = gx + 0.5f * gw, g_bry = gy + 0.5f * gh;
        float ag = gw * gh;
        if (tid == 0) scnt = 0;
        __syncthreads();

        int cnt = fcnt[b];

        // ---- pass A: per-thread top-NC iou, dense stream over PK0 ----
        float tio[NC];
        #pragma unroll
        for (int k = 0; k < NC; k++) tio[k] = 0.f;

        for (int m = tid; m < cnt; m += 256) {
            float4 c0 = PK0[bbase + m];
            float pa = (c0.z - c0.x) * (c0.w - c0.y);
            float tlx = fmaxf(g_tlx, c0.x), tly = fmaxf(g_tly, c0.y);
            float brx = fminf(g_brx, c0.z), bry = fminf(g_bry, c0.w);
            bool en = (tlx < brx) && (tly < bry);
            float ai = en ? (brx - tlx) * (bry - tly) : 0.f;
            float iou = ai / (ag + pa - ai + 1e-16f);
            if (iou > tio[NC - 1]) {
                tio[NC - 1] = iou;
                #pragma unroll
                for (int j = NC - 1; j > 0; --j) {
                    if (tio[j] > tio[j - 1]) { float t = tio[j]; tio[j] = tio[j - 1]; tio[j - 1] = t; }
                }
            }
        }

        #pragma unroll
        for (int k = 0; k < NC; k++) sio[tid * NC + k] = tio[k];
        __syncthreads();

        for (int off = 128; off > 0; off >>= 1) {
            if (tid < off) {
                int abase = tid * NC, bb2 = (tid + off) * NC;
                int i = 0, j = 0;
                float oo_[NC];
                #pragma unroll
                for (int k = 0; k < NC; k++) {
                    float va = sio[abase + i], vb = sio[bb2 + j];
                    bool ta = va >= vb;
                    oo_[k] = ta ? va : vb;
                    i += ta ? 1 : 0; j += ta ? 0 : 1;
                }
                #pragma unroll
                for (int k = 0; k < NC; k++) sio[abase + k] = oo_[k];
            }
            __syncthreads();
        }

        float s10 = 0.f;
        #pragma unroll
        for (int k = 0; k < NC; k++) s10 += sio[k];
        int dk = (int)s10;
        if (dk < 1) dk = 1;
        if (dk > NC) dk = NC;

        // ---- analytic candidate enumeration (exact reference tests) ----
        for (int lev = 0; lev < 3; lev++) {
            float s  = (lev == 0) ? 8.f : ((lev == 1) ? 16.f : 32.f);
            int   W  = (lev == 0) ? 128 : ((lev == 1) ? 64 : 32);
            int aofs = (lev == 0) ? 0 : ((lev == 1) ? NA0 : NA01);
            float rr = 2.5f * s;
            float gxr_lo = gx - rr, gxr_hi = gx + rr;
            float gyr_lo = gy - rr, gyr_hi = gy + rr;
            float lox = fmaxf(g_tlx, gxr_lo), hix = fminf(g_brx, gxr_hi);
            float loy = fmaxf(g_tly, gyr_lo), hiy = fminf(g_bry, gyr_hi);
            int ixA = (int)floorf(lox / s - 0.5f) - 1;
            int ixB = (int)ceilf (hix / s - 0.5f) + 1;
            int iyA = (int)floorf(loy / s - 0.5f) - 1;
            int iyB = (int)ceilf (hiy / s - 0.5f) + 1;
            ixA = max(ixA, 0); ixB = min(ixB, W - 1);
            iyA = max(iyA, 0); iyB = min(iyB, W - 1);
            int nx = ixB - ixA + 1, ny = iyB - iyA + 1;
            int nt = (nx > 0 && ny > 0) ? nx * ny : 0;
            for (int t = tid; t < nt; t += 256) {
                int ix = ixA + t % nx, iy = iyA + t / nx;
                float xcA = ((float)ix + 0.5f) * s;
                float ycA = ((float)iy + 0.5f) * s;
                float bl = xcA - g_tlx, brr = g_brx - xcA;
                float bt = ycA - g_tly, bbb = g_bry - ycA;
                bool inb = fminf(fminf(bl, brr), fminf(bt, bbb)) > 0.f;
                float cl = xcA - gxr_lo, cr = gxr_hi - xcA;
                float ct = ycA - gyr_lo, cb = gyr_hi - ycA;
                bool inc = fminf(fminf(cl, cr), fminf(ct, cb)) > 0.f;
                if (inb && inc) {
                    int p = atomicAdd(&scnt, 1);
                    if (p < MAXC) cand_a[p] = aofs + iy * W + ix;
                }
            }
        }
        __syncthreads();
        int nc_ = min(scnt, MAXC);

        if (dk <= nc_) {
            for (int ci = tid; ci < nc_; ci += 256) {
                int a = cand_a[ci];
                float4 c0 = A0[bbase + a];
                float pa = (c0.z - c0.x) * (c0.w - c0.y);
                float tlx = fmaxf(g_tlx, c0.x), tly = fmaxf(g_tly, c0.y);
                float brx = fminf(g_brx, c0.z), bry = fminf(g_bry, c0.w);
                bool en = (tlx < brx) && (tly < bry);
                float ai = en ? (brx - tlx) * (bry - tly) : 0.f;
                float iou = ai / (ag + pa - ai + 1e-16f);
                float c = OC[bbase + a] + 3.0f * (-__logf(iou + 1e-8f));
                cand_c[ci] = c;
                unsigned long long key = ((unsigned long long)fmono(c) << 32) | (unsigned int)g;
                atomicMin(&bestkey[bbase + a], key);
            }
            __syncthreads();
            for (int ci = tid; ci < nc_; ci += 256) {
                float c = cand_c[ci]; int a = cand_a[ci];
                int rank = 0;
                for (int j = 0; j < nc_; j++) {
                    float cj = cand_c[j]; int aj = cand_a[j];
                    rank += (cj < c || (cj == c && aj < a)) ? 1 : 0;
                }
                if (rank < dk) {
                    if (atomicAdd(&n_match[bbase + a], 1) == 0) {
                        int p = atomicAdd(&mcount[b * MSTRIDE], 1);
                        atomicExch(&mlist[b * MCAP + p], a);
                    }
                    atomicMin(&mg_min[bbase + a], g);
                }
            }
        } else {
            if (tid == 0) atomicExch(&fbflag[b], 1);
            int cnt2 = cnt;
            float fc[NC]; int fa[NC];
            #pragma unroll
            for (int k = 0; k < NC; k++) { fc[k] = 3.4e38f; fa[k] = 0x7fffffff; }
            for (int m = tid; m < cnt2; m += 256) {
                int a = PKA[bbase + m];
                float4 c0 = PK0[bbase + m];
                float pa = (c0.z - c0.x) * (c0.w - c0.y);
                float tlx = fmaxf(g_tlx, c0.x), tly = fmaxf(g_tly, c0.y);
                float brx = fminf(g_brx, c0.z), bry = fminf(g_bry, c0.w);
                bool en = (tlx < brx) && (tly < bry);
                float ai = en ? (brx - tlx) * (bry - tly) : 0.f;
                float iou = ai / (ag + pa - ai + 1e-16f);
                int xx, yy; float s2;
                if (a < NA0)       { xx = a & 127;           yy = a >> 7;  s2 = 8.f;  }
                else if (a < NA01) { int i2 = a - NA0;  xx = i2 & 63; yy = i2 >> 6; s2 = 16.f; }
                else               { int i2 = a - NA01; xx = i2 & 31; yy = i2 >> 5; s2 = 32.f; }
                float xcA = ((float)xx + 0.5f) * s2, ycA = ((float)yy + 0.5f) * s2;
                float rr2 = 2.5f * s2;
                float bl = xcA - g_tlx, brr = g_brx - xcA;
                float bt = ycA - g_tly, bbb = g_bry - ycA;
                bool inb = fminf(fminf(bl, brr), fminf(bt, bbb)) > 0.f;
                float cl = xcA - (gx - rr2), cr = (gx + rr2) - xcA;
                float ct = ycA - (gy - rr2), cb = (gy + rr2) - ycA;
                bool inc = fminf(fminf(cl, cr), fminf(ct, cb)) > 0.f;
                float c = PKO[bbase + m] + 3.0f * (-__logf(iou + 1e-8f));
                if (!(inb && inc)) c += 100000.0f;
                if (c < fc[NC - 1] || (c == fc[NC - 1] && a < fa[NC - 1])) {
                    fc[NC - 1] = c; fa[NC - 1] = a;
                    #pragma unroll
                    for (int j = NC - 1; j > 0; --j) {
                        bool sw = (fc[j] < fc[j - 1]) || (fc[j] == fc[j - 1] && fa[j] < fa[j - 1]);
                        if (sw) {
                            float t1 = fc[j]; fc[j] = fc[j - 1]; fc[j - 1] = t1;
                            int   t2 = fa[j]; fa[j] = fa[j - 1]; fa[j - 1] = t2;
                        }
                    }
                }
            }
            __syncthreads();
            #pragma unroll
            for (int k = 0; k < NC; k++) { sio[tid * NC + k] = fc[k]; si2[tid * NC + k] = fa[k]; }
            __syncthreads();
            for (int off = 128; off > 0; off >>= 1) {
                if (tid < off) {
                    int abase = tid * NC, bb2 = (tid + off) * NC;
                    int i = 0, j = 0;
                    float oc_[NC]; int oi_[NC];
                    #pragma unroll
                    for (int k = 0; k < NC; k++) {
                        float ca = sio[abase + i], cb3 = sio[bb2 + j];
                        int   ia = si2[abase + i], ib  = si2[bb2 + j];
                        bool ta = (ca < cb3) || (ca == cb3 && ia <= ib);
                        oc_[k] = ta ? ca : cb3; oi_[k] = ta ? ia : ib;
                        i += ta ? 1 : 0; j += ta ? 0 : 1;
                    }
                    #pragma unroll
                    for (int k = 0; k < NC; k++) { sio[abase + k] = oc_[k]; si2[abase + k] = oi_[k]; }
                }
                __syncthreads();
            }
            if (tid == 0) {
                for (int k = 0; k < dk; k++) {
                    int aa = si2[k];
                    if (aa != 0x7fffffff) {
                        if (atomicAdd(&n_match[bbase + aa], 1) == 0) {
                            int p = atomicAdd(&mcount[b * MSTRIDE], 1);
                            atomicExch(&mlist[b * MCAP + p], aa);
                        }
                        atomicMin(&mg_min[bbase + aa], g);
                    }
                }
            }
        }
    }

    // ---- epilogue: per-image ticket; 100th block runs sparse loss for image b ----
    __syncthreads();                       // drains all vector mem ops (incl. atomics)
    if (tid == 0) s_t = atomicAdd(&doneA[b * DSTRIDE], 1);
    __syncthreads();
    if (s_t == NG - 1) {
        __threadfence();                   // acquire: invalidate stale cache lines
        float* lbl = sio;                  // reuse LDS
        for (int i = tid; i < NG * 5; i += 256) lbl[i] = labels[b * NG * 5 + i];
        __syncthreads();

        int cm = min(mcount[b * MSTRIDE], MCAP);
        int fb = fbflag[b];
        float il_s = 0.f, ol_s = 0.f; int nf = 0;

        for (int m = tid; m < cm; m += 256) {
            int a = mlist[b * MCAP + m];
            int idx = bbase + a;
            int n = n_match[idx];

            int x, y, hw, loc; const float* objp; float s, rr;
            if (a < NA0)       { x = a & 127;            y = a >> 7;  hw = 16384; loc = y * 128 + x; objp = obj0; s = 8.f;  rr = 20.f; }
            else if (a < NA01) { int i2 = a - NA0;  x = i2 & 63; y = i2 >> 6; hw = 4096; loc = y * 64 + x; objp = obj1; s = 16.f; rr = 40.f; }
            else               { int i2 = a - NA01; x = i2 & 31; y = i2 >> 5; hw = 1024; loc = y * 32 + x; objp = obj2; s = 32.f; rr = 80.f; }

            float4 c0 = A0[idx];
            bool fg = false; int mg = 0;
            if (n == 1) { fg = true; mg = mg_min[idx]; }
            else {
                unsigned long long key = fb ? 0xFFFFFFFFFFFFFFFFull : bestkey[idx];
                if (key != 0xFFFFFFFFFFFFFFFFull) {
                    fg = true; mg = (int)(key & 0xFFFFFFFFull);
                } else {
                    // exact fallback: full 100-GT argmin (reference semantics)
                    float pa = (c0.z - c0.x) * (c0.w - c0.y);
                    float oc = OC[idx];
                    float xcA = ((float)x + 0.5f) * s, ycA = ((float)y + 0.5f) * s;
                    float bestc = 3.4e38f; int bg = 0;
                    for (int g2 = 0; g2 < NG; g2++) {
                        float l02 = lbl[g2 * 5 + 0], gx2 = lbl[g2 * 5 + 1], gy2 = lbl[g2 * 5 + 2];
                        float gw2 = lbl[g2 * 5 + 3], gh2 = lbl[g2 * 5 + 4];
                        bool gvv = (l02 + gx2 + gy2 + gw2 + gh2) > 0.f;
                        float tlx = fmaxf(gx2 - 0.5f * gw2, c0.x), tly = fmaxf(gy2 - 0.5f * gh2, c0.y);
                        float brx = fminf(gx2 + 0.5f * gw2, c0.z), bry = fminf(gy2 + 0.5f * gh2, c0.w);
                        bool en = (tlx < brx) && (tly < bry);
                        float ai = en ? (brx - tlx) * (bry - tly) : 0.f;
                        float iou = ai / (gw2 * gh2 + pa - ai + 1e-16f);
                        float bl = xcA - (gx2 - 0.5f * gw2), br = (gx2 + 0.5f * gw2) - xcA;
                        float bt = ycA - (gy2 - 0.5f * gh2), bb = (gy2 + 0.5f * gh2) - ycA;
                        bool inb = fminf(fminf(bl, br), fminf(bt, bb)) > 0.f;
                        float cl = xcA - (gx2 - rr), cr = (gx2 + rr) - xcA;
                        float ct = ycA - (gy2 - rr), cb = (gy2 + rr) - ycA;
                        bool inc = fminf(fminf(cl, cr), fminf(ct, cb)) > 0.f;
                        float c = oc + 3.0f * (-__logf(iou + 1e-8f));
                        if (!(inb && inc)) c += 100000.0f;
                        if (!gvv)          c += 10000000.0f;
                        if (c < bestc) { bestc = c; bg = g2; }
                    }
                    bool gvv = (lbl[bg * 5 + 0] + lbl[bg * 5 + 1] + lbl[bg * 5 + 2] +
                                lbl[bg * 5 + 3] + lbl[bg * 5 + 4]) > 0.f;
                    if (gvv) { fg = true; mg = bg; }
                }
            }

            if (fg) {
                float pa = (c0.z - c0.x) * (c0.w - c0.y);
                float gx2 = lbl[mg * 5 + 1], gy2 = lbl[mg * 5 + 2];
                float gw2 = lbl[mg * 5 + 3], gh2 = lbl[mg * 5 + 4];
                float tlx = fmaxf(c0.x, gx2 - 0.5f * gw2);
                float tly = fmaxf(c0.y, gy2 - 0.5f * gh2);
                float brx = fminf(c0.z, gx2 + 0.5f * gw2);
                float bry = fminf(c0.w, gy2 + 0.5f * gh2);
                bool en = (tlx < brx) && (tly < bry);
                float ai = en ? (brx - tlx) * (bry - tly) : 0.f;
                float iou = ai / (pa + gw2 * gh2 - ai + 1e-16f);
                il_s += 1.f - iou * iou;
                ol_s += objp[b * hw + loc];
                nf++;
            }
        }

        for (int off = 32; off > 0; off >>= 1) {
            il_s += __shfl_down(il_s, off);
            ol_s += __shfl_down(ol_s, off);
            nf   += __shfl_down(nf, off);
        }
        __shared__ float wI[4], wO[4];
        __shared__ int   wN[4];
        int wid = tid >> 6;
        if ((tid & 63) == 0) { wI[wid] = il_s; wO[wid] = ol_s; wN[wid] = nf; }
        __syncthreads();
        if (tid == 0) {
            pIl2[b] = wI[0] + wI[1] + wI[2] + wI[3];
            pOl[b]  = wO[0] + wO[1] + wO[2] + wO[3];
            pNf2[b] = wN[0] + wN[1] + wN[2] + wN[3];
            __threadfence();               // release: flush partials
            s_g = atomicAdd(gdone, 1);
        }
        __syncthreads();

        // ---- global ticket: 16th image-block finalizes ----
        if (s_g == NB - 1) {
            __threadfence();
            double dSp = 0.0;
            for (int i = tid; i < NBLK; i += 256) dSp += (double)pSp[i];
            double dIl = 0.0, dOl = 0.0; int nf2 = 0;
            if (tid < NB) {
                dIl = (double)pIl2[tid];
                dOl = (double)pOl[tid];
                nf2 = pNf2[tid];
            }
            int ng = 0;
            for (int i = tid; i < NB * NG; i += 256) {
                const float* L2 = labels + i * 5;
                if (L2[0] + L2[1] + L2[2] + L2[3] + L2[4] > 0.f) ng++;
            }
            for (int off = 32; off > 0; off >>= 1) {
                dSp += __shfl_down(dSp, off);
                dIl += __shfl_down(dIl, off);
                dOl += __shfl_down(dOl, off);
                nf2 += __shfl_down(nf2, off);
                ng  += __shfl_down(ng, off);
            }
            __shared__ double fSp[4], fIl[4], fOl[4];
            __shared__ int fNf[4], fNg[4];
            if ((tid & 63) == 0) { fSp[wid] = dSp; fIl[wid] = dIl; fOl[wid] = dOl; fNf[wid] = nf2; fNg[wid] = ng; }
            __syncthreads();
            if (tid == 0) {
                double tSp = fSp[0] + fSp[1] + fSp[2] + fSp[3];
                double tIl = fIl[0] + fIl[1] + fIl[2] + fIl[3];
                double tOl = fOl[0] + fOl[1] + fOl[2] + fOl[3];
                int tNf = fNf[0] + fNf[1] + fNf[2] + fNf[3];
                int tNg = fNg[0] + fNg[1] + fNg[2] + fNg[3];
                float num_fg  = fmaxf((float)tNf, 1.f);
                float num_gts = fmaxf((float)tNg, 1.f);
                float li = (float)(tIl / (double)num_fg);
                float lo = (float)((tSp - tOl) / (double)num_fg);
                out[0] = 5.f * li + lo;
                out[1] = 5.f * li;
                out[2] = lo;
                out[3] = 0.f;
                out[4] = num_fg / num_gts;
            }
        }
    }
}

extern "C" void kernel_launch(void* const* d_in, const int* in_sizes, int n_in,
                              void* d_out, int out_size, void* d_ws, size_t ws_size,
                              hipStream_t stream)
{
    const float* reg0   = (const float*)d_in[0];
    const float* obj0   = (const float*)d_in[1];
    const float* reg1   = (const float*)d_in[2];
    const float* obj1   = (const float*)d_in[3];
    const float* reg2   = (const float*)d_in[4];
    const float* obj2   = (const float*)d_in[5];
    const float* labels = (const float*)d_in[6];
    float* out = (float*)d_out;

    char* w = (char*)d_ws;
    size_t off = 0;
    int*    doneA  = (int*)(w + off);     off += (size_t)NB * DSTRIDE * 4;   // zeroed below
    int*    gdone  = (int*)(w + off);     off += 256;                        // zeroed below
    int*    mcount = (int*)(w + off);     off += (size_t)NB * MSTRIDE * 4;
    int*    bcnt   = (int*)(w + off);     off += (size_t)NB * NCHK * 4;
    int*    fcnt   = (int*)(w + off);     off += (size_t)NB * 4;
    int*    fbflag = (int*)(w + off);     off += (size_t)NB * 4;
    float*  pSp    = (float*)(w + off);   off += (size_t)NBLK * 4;
    float*  pIl2   = (float*)(w + off);   off += (size_t)NB * 4;
    float*  pOl    = (float*)(w + off);   off += (size_t)NB * 4;
    int*    pNf2   = (int*)(w + off);     off += (size_t)NB * 4;
    off = (off + 255) & ~(size_t)255;
    float4* A0      = (float4*)(w + off); off += (size_t)NB * NA * 16;
    float4* PK0     = (float4*)(w + off); off += (size_t)NB * NA * 16;
    unsigned long long* bestkey = (unsigned long long*)(w + off); off += (size_t)NB * NA * 8;
    float*  OC      = (float*)(w + off);  off += (size_t)NB * NA * 4;
    float*  PKO     = (float*)(w + off);  off += (size_t)NB * NA * 4;
    int*    PKA     = (int*)(w + off);    off += (size_t)NB * NA * 4;
    int*    cidx    = (int*)(w + off);    off += (size_t)NB * NA * 4;
    int*    n_match = (int*)(w + off);    off += (size_t)NB * NA * 4;
    int*    mg_min  = (int*)(w + off);    off += (size_t)NB * NA * 4;
    int*    mlist   = (int*)(w + off);    off += (size_t)NB * MCAP * 4;

    dim3 gA(NCHK, NB);   // 84 x 16

    hipMemsetAsync(doneA, 0, (size_t)NB * DSTRIDE * 4 + 256, stream);  // tickets
    k_decode<<<gA, 256, 0, stream>>>(reg0, obj0, reg1, obj1, reg2, obj2, labels,
                                     A0, OC, cidx, bcnt, pSp);
    k_pack<<<gA, 256, 0, stream>>>(A0, OC, cidx, bcnt, PK0, PKO, PKA, fcnt,
                                   n_match, mg_min, bestkey, mcount, fbflag);
    k_assign<<<dim3(NB * NG), 256, 0, stream>>>(labels, A0, OC, obj0, obj1, obj2,
                                                PK0, PKO, PKA, fcnt,
                                                n_match, mg_min, mlist, mcount,
                                                bestkey, fbflag, pSp,
                                                pIl2, pOl, pNf2, doneA, gdone, out);
}

// Round 13
// 121.983 us; speedup vs baseline: 1.0566x; 1.0566x over previous
//
#include <hip/hip_runtime.h>
#include <math.h>

#define NA   21504   // 128^2 + 64^2 + 32^2
#define NA0  16384
#define NA01 20480
#define NG   100
#define NB   16
#define NC   10      // N_CAND
#define NCHK 84      // 256-anchor chunks per image
#define NBLK 1344    // NCHK * NB
#define MAXC 192     // candidate cap (true max in_both = 75)
#define MCAP 1024    // matched-anchor list capacity (true max = 100*10)
#define MSTRIDE 64   // ints between mcount[b] entries (256B: one line each)
#define NSQ  4       // k_sparse blocks per image

__device__ __forceinline__ float softplusf(float x) {
    return fmaxf(x, 0.f) + log1pf(expf(-fabsf(x)));
}

// monotone float->u32 mapping: a<b  <=>  map(a)<map(b)
__device__ __forceinline__ unsigned int fmono(float f) {
    unsigned int u = __float_as_uint(f);
    return (f < 0.f) ? ~u : (u | 0x80000000u);
}

// ---------------- decode + in-block raster + chunked compaction ----------------
// A0/OC written ONLY for fg anchors (all downstream consumers are fg-only).
__global__ __launch_bounds__(256) void k_decode(
    const float* __restrict__ reg0, const float* __restrict__ obj0,
    const float* __restrict__ reg1, const float* __restrict__ obj1,
    const float* __restrict__ reg2, const float* __restrict__ obj2,
    const float* __restrict__ labels,
    float4* __restrict__ A0, float* __restrict__ OC,
    int* __restrict__ cidx, int* __restrict__ bcnt,
    float* __restrict__ pSp)
{
    int b  = blockIdx.y;
    int bx = blockIdx.x;
    int tid = threadIdx.x;
    int a = bx * 256 + tid;

    int W, ry0, rows; float s;
    if (bx < 64)      { W = 128; s = 8.f;  ry0 = bx * 2;        rows = 2; }
    else if (bx < 80) { W = 64;  s = 16.f; ry0 = (bx - 64) * 4; rows = 4; }
    else              { W = 32;  s = 32.f; ry0 = (bx - 80) * 8; rows = 8; }

    __shared__ unsigned int smask[8];
    if (tid < 8) smask[tid] = 0u;
    __syncthreads();

    // raster: thread g<100 rasterizes GT g's (box ∪ center) rect ∩ this block's rows
    if (tid < NG) {
        const float* L = labels + (b * NG + tid) * 5;
        float gx = L[1], gy = L[2], gw = L[3], gh = L[4];
        float r = 2.5f * s;
        float tlx = gx - 0.5f * gw, tly = gy - 0.5f * gh;
        float brx = gx + 0.5f * gw, bry = gy + 0.5f * gh;
        float cxl = gx - r, cxh = gx + r, cyl = gy - r, cyh = gy + r;
        float lox = fminf(tlx, cxl), hix = fmaxf(brx, cxh);
        float loy = fminf(tly, cyl), hiy = fmaxf(bry, cyh);
        int ixA = (int)floorf(lox / s - 0.5f) - 1;
        int ixB = (int)ceilf (hix / s - 0.5f) + 1;
        int iyA = (int)floorf(loy / s - 0.5f) - 1;
        int iyB = (int)ceilf (hiy / s - 0.5f) + 1;
        ixA = max(ixA, 0); ixB = min(ixB, W - 1);
        iyA = max(iyA, ry0); iyB = min(iyB, ry0 + rows - 1);
        for (int iy = iyA; iy <= iyB; iy++) {
            float yc = ((float)iy + 0.5f) * s;
            float mb = fminf(yc - tly, bry - yc);
            float mc = fminf(yc - cyl, cyh - yc);
            for (int ix = ixA; ix <= ixB; ix++) {
                float xc = ((float)ix + 0.5f) * s;
                bool inb = fminf(fminf(xc - tlx, brx - xc), mb) > 0.f;
                bool inc = fminf(fminf(xc - cxl, cxh - xc), mc) > 0.f;
                if (inb || inc) {
                    int bit = (iy - ry0) * W + ix;
                    atomicOr(&smask[bit >> 5], 1u << (bit & 31));
                }
            }
        }
    }

    int x, y, hw, loc;
    const float* regp; const float* objp;
    if (a < NA0)       { x = a & 127;           y = a >> 7; hw = 16384; loc = y * 128 + x; regp = reg0; objp = obj0; }
    else if (a < NA01) { int i = a - NA0;  x = i & 63; y = i >> 6; hw = 4096;  loc = y * 64 + x;  regp = reg1; objp = obj1; }
    else               { int i = a - NA01; x = i & 31; y = i >> 5; hw = 1024;  loc = y * 32 + x;  regp = reg2; objp = obj2; }

    float r0 = regp[(b * 4 + 0) * hw + loc];
    float r1 = regp[(b * 4 + 1) * hw + loc];
    float r2 = regp[(b * 4 + 2) * hw + loc];
    float r3 = regp[(b * 4 + 3) * hw + loc];
    float ol = objp[b * hw + loc];

    float px = (r0 + (float)x) * s, py = (r1 + (float)y) * s;
    float pw = expf(r2) * s,        ph = expf(r3) * s;
    float ocv = softplusf(-ol);

    __syncthreads();                      // raster bitmap complete
    bool fga = (smask[tid >> 5] >> (tid & 31)) & 1u;

    int idx = b * NA + a;
    if (fga) {
        A0[idx] = make_float4(px - 0.5f * pw, py - 0.5f * ph, px + 0.5f * pw, py + 0.5f * ph);
        OC[idx] = ocv;
    }

    // per-block partial of softplus(ol) = OC + ol  (exact)
    float sp = ocv + ol;
    for (int off = 32; off > 0; off >>= 1) sp += __shfl_down(sp, off);

    unsigned long long mask = __ballot(fga);
    int lane = tid & 63, wid = tid >> 6;
    __shared__ float wSp[4];
    __shared__ int   wcnt[4];
    if (lane == 0) { wSp[wid] = sp; wcnt[wid] = __popcll(mask); }
    __syncthreads();
    int wbase = 0;
    #pragma unroll
    for (int w2 = 0; w2 < 4; w2++) if (w2 < wid) wbase += wcnt[w2];
    if (fga) {
        int prefix = __popcll(mask & ((1ull << lane) - 1ull));
        cidx[b * NA + bx * 256 + wbase + prefix] = a;
    }
    if (tid == 0) {
        bcnt[b * NCHK + bx] = wcnt[0] + wcnt[1] + wcnt[2] + wcnt[3];
        pSp[b * NCHK + bx]  = wSp[0] + wSp[1] + wSp[2] + wSp[3];
    }
}

// ---------------- pack into dense arrays + init match scratch (fg-only) ----------------
__global__ __launch_bounds__(256) void k_pack(
    const float4* __restrict__ A0, const float* __restrict__ OC,
    const int* __restrict__ cidx, const int* __restrict__ bcnt,
    float4* __restrict__ PK0, float* __restrict__ PKO, int* __restrict__ PKA,
    int* __restrict__ fcnt,
    int* __restrict__ n_match, int* __restrict__ mg_min,
    unsigned long long* __restrict__ bestkey,
    int* __restrict__ mcount, int* __restrict__ fbflag)
{
    int b = blockIdx.y, bx = blockIdx.x, tid = threadIdx.x;
    int v = 0;
    for (int i = tid; i < bx; i += 256) v += bcnt[b * NCHK + i];
    for (int off = 32; off > 0; off >>= 1) v += __shfl_down(v, off);
    __shared__ int ws[4];
    int wid = tid >> 6;
    if ((tid & 63) == 0) ws[wid] = v;
    __syncthreads();
    int base = ws[0] + ws[1] + ws[2] + ws[3];
    int nt = bcnt[b * NCHK + bx];
    if (tid < nt) {
        int a = cidx[b * NA + bx * 256 + tid];
        int idx = b * NA + a;
        int d = b * NA + base + tid;
        PK0[d] = A0[idx];
        PKO[d] = OC[idx];
        PKA[d] = a;
        n_match[idx] = 0;
        mg_min[idx]  = 0x7fffffff;
        bestkey[idx] = 0xFFFFFFFFFFFFFFFFull;
    }
    if (bx == NCHK - 1 && tid == 0) fcnt[b] = base + nt;
    if (bx == 0 && tid == 0) { mcount[b * MSTRIDE] = 0; fbflag[b] = 0; }
}

// ---------------- per-(b,g) assignment: iou top-10 (early-reject) + candidates ----------------
__global__ __launch_bounds__(256) void k_assign(
    const float* __restrict__ labels, const float4* __restrict__ A0,
    const float* __restrict__ OC,
    const float4* __restrict__ PK0, const float* __restrict__ PKO,
    const int* __restrict__ PKA, const int* __restrict__ fcnt,
    int* __restrict__ n_match, int* __restrict__ mg_min,
    int* __restrict__ mlist, int* __restrict__ mcount,
    unsigned long long* __restrict__ bestkey, int* __restrict__ fbflag)
{
    int blk = blockIdx.x;
    int b = blk / NG, g = blk % NG;
    const float* L = labels + (b * NG + g) * 5;
    float l0 = L[0], gx = L[1], gy = L[2], gw = L[3], gh = L[4];
    bool gv = (l0 + gx + gy + gw + gh) > 0.f;
    if (!gv) return;
    int tid = threadIdx.x;

    float g_tlx = gx - 0.5f * gw, g_tly = gy - 0.5f * gh;
    float g_brx = gx + 0.5f * gw, g_bry = gy + 0.5f * gh;
    float ag = gw * gh;
    int bbase = b * NA;

    __shared__ float sio[256 * NC];
    __shared__ int   si2[256 * NC];
    __shared__ int   cand_a[MAXC];
    __shared__ float cand_c[MAXC];
    __shared__ int   scnt;
    if (tid == 0) scnt = 0;
    __syncthreads();

    int cnt = fcnt[b];

    // ---- pass A: per-thread top-NC iou, dense stream, exact early-reject ----
    // Non-overlapping pairs have iou == 0 exactly (ai=0, denom>0) and tio init 0
    // with strict '>', so skipping them is bit-identical.
    float tio[NC];
    #pragma unroll
    for (int k = 0; k < NC; k++) tio[k] = 0.f;

    for (int m = tid; m < cnt; m += 256) {
        float4 c0 = PK0[bbase + m];
        float tlx = fmaxf(g_tlx, c0.x), tly = fmaxf(g_tly, c0.y);
        float brx = fminf(g_brx, c0.z), bry = fminf(g_bry, c0.w);
        if (tlx < brx && tly < bry) {
            float ai = (brx - tlx) * (bry - tly);
            float pa = (c0.z - c0.x) * (c0.w - c0.y);
            float iou = ai / (ag + pa - ai + 1e-16f);
            if (iou > tio[NC - 1]) {
                tio[NC - 1] = iou;
                #pragma unroll
                for (int j = NC - 1; j > 0; --j) {
                    if (tio[j] > tio[j - 1]) { float t = tio[j]; tio[j] = tio[j - 1]; tio[j - 1] = t; }
                }
            }
        }
    }

    #pragma unroll
    for (int k = 0; k < NC; k++) sio[tid * NC + k] = tio[k];
    __syncthreads();

    for (int off = 128; off > 0; off >>= 1) {
        if (tid < off) {
            int abase = tid * NC, bb2 = (tid + off) * NC;
            int i = 0, j = 0;
            float oo_[NC];
            #pragma unroll
            for (int k = 0; k < NC; k++) {
                float va = sio[abase + i], vb = sio[bb2 + j];
                bool ta = va >= vb;
                oo_[k] = ta ? va : vb;
                i += ta ? 1 : 0; j += ta ? 0 : 1;
            }
            #pragma unroll
            for (int k = 0; k < NC; k++) sio[abase + k] = oo_[k];
        }
        __syncthreads();
    }

    float s10 = 0.f;
    #pragma unroll
    for (int k = 0; k < NC; k++) s10 += sio[k];
    int dk = (int)s10;
    if (dk < 1) dk = 1;
    if (dk > NC) dk = NC;

    // ---- analytic candidate enumeration (exact reference tests) ----
    for (int lev = 0; lev < 3; lev++) {
        float s  = (lev == 0) ? 8.f : ((lev == 1) ? 16.f : 32.f);
        int   W  = (lev == 0) ? 128 : ((lev == 1) ? 64 : 32);
        int aofs = (lev == 0) ? 0 : ((lev == 1) ? NA0 : NA01);
        float rr = 2.5f * s;
        float gxr_lo = gx - rr, gxr_hi = gx + rr;
        float gyr_lo = gy - rr, gyr_hi = gy + rr;
        float lox = fmaxf(g_tlx, gxr_lo), hix = fminf(g_brx, gxr_hi);
        float loy = fmaxf(g_tly, gyr_lo), hiy = fminf(g_bry, gyr_hi);
        int ixA = (int)floorf(lox / s - 0.5f) - 1;
        int ixB = (int)ceilf (hix / s - 0.5f) + 1;
        int iyA = (int)floorf(loy / s - 0.5f) - 1;
        int iyB = (int)ceilf (hiy / s - 0.5f) + 1;
        ixA = max(ixA, 0); ixB = min(ixB, W - 1);
        iyA = max(iyA, 0); iyB = min(iyB, W - 1);
        int nx = ixB - ixA + 1, ny = iyB - iyA + 1;
        int nt = (nx > 0 && ny > 0) ? nx * ny : 0;
        for (int t = tid; t < nt; t += 256) {
            int ix = ixA + t % nx, iy = iyA + t / nx;
            float xcA = ((float)ix + 0.5f) * s;
            float ycA = ((float)iy + 0.5f) * s;
            float bl = xcA - g_tlx, brr = g_brx - xcA;
            float bt = ycA - g_tly, bbb = g_bry - ycA;
            bool inb = fminf(fminf(bl, brr), fminf(bt, bbb)) > 0.f;
            float cl = xcA - gxr_lo, cr = gxr_hi - xcA;
            float ct = ycA - gyr_lo, cb = gyr_hi - ycA;
            bool inc = fminf(fminf(cl, cr), fminf(ct, cb)) > 0.f;
            if (inb && inc) {
                int p = atomicAdd(&scnt, 1);
                if (p < MAXC) cand_a[p] = aofs + iy * W + ix;
            }
        }
    }
    __syncthreads();
    int nc_ = min(scnt, MAXC);

    if (dk <= nc_) {
        for (int ci = tid; ci < nc_; ci += 256) {
            int a = cand_a[ci];
            float4 c0 = A0[bbase + a];
            float pa = (c0.z - c0.x) * (c0.w - c0.y);
            float tlx = fmaxf(g_tlx, c0.x), tly = fmaxf(g_tly, c0.y);
            float brx = fminf(g_brx, c0.z), bry = fminf(g_bry, c0.w);
            bool en = (tlx < brx) && (tly < bry);
            float ai = en ? (brx - tlx) * (bry - tly) : 0.f;
            float iou = ai / (ag + pa - ai + 1e-16f);
            float c = OC[bbase + a] + 3.0f * (-__logf(iou + 1e-8f));
            cand_c[ci] = c;
            unsigned long long key = ((unsigned long long)fmono(c) << 32) | (unsigned int)g;
            atomicMin(&bestkey[bbase + a], key);
        }
        __syncthreads();
        for (int ci = tid; ci < nc_; ci += 256) {
            float c = cand_c[ci]; int a = cand_a[ci];
            int rank = 0;
            for (int j = 0; j < nc_; j++) {
                float cj = cand_c[j]; int aj = cand_a[j];
                rank += (cj < c || (cj == c && aj < a)) ? 1 : 0;
            }
            if (rank < dk) {
                if (atomicAdd(&n_match[bbase + a], 1) == 0) {
                    int p = atomicAdd(&mcount[b * MSTRIDE], 1);
                    mlist[b * MCAP + p] = a;
                }
                atomicMin(&mg_min[bbase + a], g);
            }
        }
    } else {
        // ---- rare fallback: full cost scan over dense packed list ----
        if (tid == 0) fbflag[b] = 1;
        float fc[NC]; int fa[NC];
        #pragma unroll
        for (int k = 0; k < NC; k++) { fc[k] = 3.4e38f; fa[k] = 0x7fffffff; }
        for (int m = tid; m < cnt; m += 256) {
            int a = PKA[bbase + m];
            float4 c0 = PK0[bbase + m];
            float pa = (c0.z - c0.x) * (c0.w - c0.y);
            float tlx = fmaxf(g_tlx, c0.x), tly = fmaxf(g_tly, c0.y);
            float brx = fminf(g_brx, c0.z), bry = fminf(g_bry, c0.w);
            bool en = (tlx < brx) && (tly < bry);
            float ai = en ? (brx - tlx) * (bry - tly) : 0.f;
            float iou = ai / (ag + pa - ai + 1e-16f);
            int xx, yy; float s2;
            if (a < NA0)       { xx = a & 127;           yy = a >> 7;  s2 = 8.f;  }
            else if (a < NA01) { int i2 = a - NA0;  xx = i2 & 63; yy = i2 >> 6; s2 = 16.f; }
            else               { int i2 = a - NA01; xx = i2 & 31; yy = i2 >> 5; s2 = 32.f; }
            float xcA = ((float)xx + 0.5f) * s2, ycA = ((float)yy + 0.5f) * s2;
            float rr2 = 2.5f * s2;
            float bl = xcA - g_tlx, brr = g_brx - xcA;
            float bt = ycA - g_tly, bbb = g_bry - ycA;
            bool inb = fminf(fminf(bl, brr), fminf(bt, bbb)) > 0.f;
            float cl = xcA - (gx - rr2), cr = (gx + rr2) - xcA;
            float ct = ycA - (gy - rr2), cb = (gy + rr2) - ycA;
            bool inc = fminf(fminf(cl, cr), fminf(ct, cb)) > 0.f;
            float c = PKO[bbase + m] + 3.0f * (-__logf(iou + 1e-8f));
            if (!(inb && inc)) c += 100000.0f;
            if (c < fc[NC - 1] || (c == fc[NC - 1] && a < fa[NC - 1])) {
                fc[NC - 1] = c; fa[NC - 1] = a;
                #pragma unroll
                for (int j = NC - 1; j > 0; --j) {
                    bool sw = (fc[j] < fc[j - 1]) || (fc[j] == fc[j - 1] && fa[j] < fa[j - 1]);
                    if (sw) {
                        float t1 = fc[j]; fc[j] = fc[j - 1]; fc[j - 1] = t1;
                        int   t2 = fa[j]; fa[j] = fa[j - 1]; fa[j - 1] = t2;
                    }
                }
            }
        }
        __syncthreads();
        #pragma unroll
        for (int k = 0; k < NC; k++) { sio[tid * NC + k] = fc[k]; si2[tid * NC + k] = fa[k]; }
        __syncthreads();
        for (int off = 128; off > 0; off >>= 1) {
            if (tid < off) {
                int abase = tid * NC, bb2 = (tid + off) * NC;
                int i = 0, j = 0;
                float oc_[NC]; int oi_[NC];
                #pragma unroll
                for (int k = 0; k < NC; k++) {
                    float ca = sio[abase + i], cb3 = sio[bb2 + j];
                    int   ia = si2[abase + i], ib  = si2[bb2 + j];
                    bool ta = (ca < cb3) || (ca == cb3 && ia <= ib);
                    oc_[k] = ta ? ca : cb3; oi_[k] = ta ? ia : ib;
                    i += ta ? 1 : 0; j += ta ? 0 : 1;
                }
                #pragma unroll
                for (int k = 0; k < NC; k++) { sio[abase + k] = oc_[k]; si2[abase + k] = oi_[k]; }
            }
            __syncthreads();
        }
        if (tid == 0) {
            for (int k = 0; k < dk; k++) {
                int aa = si2[k];
                if (aa != 0x7fffffff) {
                    if (atomicAdd(&n_match[bbase + aa], 1) == 0) {
                        int p = atomicAdd(&mcount[b * MSTRIDE], 1);
                        mlist[b * MCAP + p] = aa;
                    }
                    atomicMin(&mg_min[bbase + aa], g);
                }
            }
        }
    }
}

// ---------------- sparse loss over matched anchors (NSQ blocks per image) ----------------
__global__ __launch_bounds__(256) void k_sparse(
    const float* __restrict__ labels,
    const float* __restrict__ obj0, const float* __restrict__ obj1,
    const float* __restrict__ obj2,
    const float4* __restrict__ A0, const float* __restrict__ OC,
    const int* __restrict__ n_match, const int* __restrict__ mg_min,
    const int* __restrict__ mlist, const int* __restrict__ mcount,
    const unsigned long long* __restrict__ bestkey, const int* __restrict__ fbflag,
    float* __restrict__ pIl2, float* __restrict__ pOl, int* __restrict__ pNf2)
{
    int q = blockIdx.x;
    int b = blockIdx.y;
    int tid = threadIdx.x;
    __shared__ float lbl[NG * 5];
    for (int i = tid; i < NG * 5; i += 256) lbl[i] = labels[b * NG * 5 + i];
    __syncthreads();

    int cm = min(mcount[b * MSTRIDE], MCAP);
    int fb = fbflag[b];
    float il_s = 0.f, ol_s = 0.f; int nf = 0;

    for (int m = q * 256 + tid; m < cm; m += NSQ * 256) {
        int a = mlist[b * MCAP + m];
        int idx = b * NA + a;
        int n = n_match[idx];

        int x, y, hw, loc; const float* objp; float s, rr;
        if (a < NA0)       { x = a & 127;            y = a >> 7;  hw = 16384; loc = y * 128 + x; objp = obj0; s = 8.f;  rr = 20.f; }
        else if (a < NA01) { int i2 = a - NA0;  x = i2 & 63; y = i2 >> 6; hw = 4096; loc = y * 64 + x; objp = obj1; s = 16.f; rr = 40.f; }
        else               { int i2 = a - NA01; x = i2 & 31; y = i2 >> 5; hw = 1024; loc = y * 32 + x; objp = obj2; s = 32.f; rr = 80.f; }

        float4 c0 = A0[idx];
        bool fg = false; int mg = 0;
        if (n == 1) { fg = true; mg = mg_min[idx]; }
        else {
            unsigned long long key = fb ? 0xFFFFFFFFFFFFFFFFull : bestkey[idx];
            if (key != 0xFFFFFFFFFFFFFFFFull) {
                fg = true; mg = (int)(key & 0xFFFFFFFFull);
            } else {
                // exact fallback: full 100-GT argmin (reference semantics)
                float pa = (c0.z - c0.x) * (c0.w - c0.y);
                float oc = OC[idx];
                float xcA = ((float)x + 0.5f) * s, ycA = ((float)y + 0.5f) * s;
                float bestc = 3.4e38f; int bg = 0;
                for (int g = 0; g < NG; g++) {
                    float l0 = lbl[g * 5 + 0], gx = lbl[g * 5 + 1], gy = lbl[g * 5 + 2];
                    float gw = lbl[g * 5 + 3], gh = lbl[g * 5 + 4];
                    bool gvv = (l0 + gx + gy + gw + gh) > 0.f;
                    float tlx = fmaxf(gx - 0.5f * gw, c0.x), tly = fmaxf(gy - 0.5f * gh, c0.y);
                    float brx = fminf(gx + 0.5f * gw, c0.z), bry = fminf(gy + 0.5f * gh, c0.w);
                    bool en = (tlx < brx) && (tly < bry);
                    float ai = en ? (brx - tlx) * (bry - tly) : 0.f;
                    float iou = ai / (gw * gh + pa - ai + 1e-16f);
                    float bl = xcA - (gx - 0.5f * gw), br = (gx + 0.5f * gw) - xcA;
                    float bt = ycA - (gy - 0.5f * gh), bb = (gy + 0.5f * gh) - ycA;
                    bool inb = fminf(fminf(bl, br), fminf(bt, bb)) > 0.f;
                    float cl = xcA - (gx - rr), cr = (gx + rr) - xcA;
                    float ct = ycA - (gy - rr), cb = (gy + rr) - ycA;
                    bool inc = fminf(fminf(cl, cr), fminf(ct, cb)) > 0.f;
                    float c = oc + 3.0f * (-__logf(iou + 1e-8f));
                    if (!(inb && inc)) c += 100000.0f;
                    if (!gvv)          c += 10000000.0f;
                    if (c < bestc) { bestc = c; bg = g; }
                }
                bool gvv = (lbl[bg * 5 + 0] + lbl[bg * 5 + 1] + lbl[bg * 5 + 2] +
                            lbl[bg * 5 + 3] + lbl[bg * 5 + 4]) > 0.f;
                if (gvv) { fg = true; mg = bg; }
            }
        }

        if (fg) {
            float pa = (c0.z - c0.x) * (c0.w - c0.y);
            float gx = lbl[mg * 5 + 1], gy = lbl[mg * 5 + 2];
            float gw = lbl[mg * 5 + 3], gh = lbl[mg * 5 + 4];
            float tlx = fmaxf(c0.x, gx - 0.5f * gw);
            float tly = fmaxf(c0.y, gy - 0.5f * gh);
            float brx = fminf(c0.z, gx + 0.5f * gw);
            float bry = fminf(c0.w, gy + 0.5f * gh);
            bool en = (tlx < brx) && (tly < bry);
            float ai = en ? (brx - tlx) * (bry - tly) : 0.f;
            float iou = ai / (pa + gw * gh - ai + 1e-16f);
            il_s += 1.f - iou * iou;
            ol_s += objp[b * hw + loc];
            nf++;
        }
    }

    for (int off = 32; off > 0; off >>= 1) {
        il_s += __shfl_down(il_s, off);
        ol_s += __shfl_down(ol_s, off);
        nf   += __shfl_down(nf, off);
    }
    __shared__ float wI[4], wO[4];
    __shared__ int   wN[4];
    int wid = tid >> 6;
    if ((tid & 63) == 0) { wI[wid] = il_s; wO[wid] = ol_s; wN[wid] = nf; }
    __syncthreads();
    if (tid == 0) {
        int pb = b * NSQ + q;
        pIl2[pb] = wI[0] + wI[1] + wI[2] + wI[3];
        pOl[pb]  = wO[0] + wO[1] + wO[2] + wO[3];
        pNf2[pb] = wN[0] + wN[1] + wN[2] + wN[3];
    }
}

// ---------------- finalize ----------------
__global__ __launch_bounds__(256) void k_fin(
    const float* __restrict__ pSp, const float* __restrict__ pIl2,
    const float* __restrict__ pOl, const int* __restrict__ pNf2,
    const float* __restrict__ labels, float* __restrict__ out)
{
    int tid = threadIdx.x;
    double dSp = 0.0;
    for (int i = tid; i < NBLK; i += 256) dSp += (double)pSp[i];
    double dIl = 0.0, dOl = 0.0; int nf = 0;
    for (int i = tid; i < NB * NSQ; i += 256) {
        dIl += (double)pIl2[i];
        dOl += (double)pOl[i];
        nf  += pNf2[i];
    }
    int ng = 0;
    for (int i = tid; i < NB * NG; i += 256) {
        const float* L = labels + i * 5;
        if (L[0] + L[1] + L[2] + L[3] + L[4] > 0.f) ng++;
    }
    for (int off = 32; off > 0; off >>= 1) {
        dSp += __shfl_down(dSp, off);
        dIl += __shfl_down(dIl, off);
        dOl += __shfl_down(dOl, off);
        nf  += __shfl_down(nf, off);
        ng  += __shfl_down(ng, off);
    }
    __shared__ double sSp[4], sIl[4], sOl[4];
    __shared__ int sNf[4], sNg[4];
    int wid = tid >> 6;
    if ((tid & 63) == 0) { sSp[wid] = dSp; sIl[wid] = dIl; sOl[wid] = dOl; sNf[wid] = nf; sNg[wid] = ng; }
    __syncthreads();
    if (tid == 0) {
        double tSp = sSp[0] + sSp[1] + sSp[2] + sSp[3];
        double tIl = sIl[0] + sIl[1] + sIl[2] + sIl[3];
        double tOl = sOl[0] + sOl[1] + sOl[2] + sOl[3];
        int tNf = sNf[0] + sNf[1] + sNf[2] + sNf[3];
        int tNg = sNg[0] + sNg[1] + sNg[2] + sNg[3];
        float num_fg  = fmaxf((float)tNf, 1.f);
        float num_gts = fmaxf((float)tNg, 1.f);
        float li = (float)(tIl / (double)num_fg);
        float lo = (float)((tSp - tOl) / (double)num_fg);
        out[0] = 5.f * li + lo;
        out[1] = 5.f * li;
        out[2] = lo;
        out[3] = 0.f;
        out[4] = num_fg / num_gts;
    }
}

extern "C" void kernel_launch(void* const* d_in, const int* in_sizes, int n_in,
                              void* d_out, int out_size, void* d_ws, size_t ws_size,
                              hipStream_t stream)
{
    const float* reg0   = (const float*)d_in[0];
    const float* obj0   = (const float*)d_in[1];
    const float* reg1   = (const float*)d_in[2];
    const float* obj1   = (const float*)d_in[3];
    const float* reg2   = (const float*)d_in[4];
    const float* obj2   = (const float*)d_in[5];
    const float* labels = (const float*)d_in[6];
    float* out = (float*)d_out;

    char* w = (char*)d_ws;
    size_t off = 0;
    int*    mcount = (int*)(w + off);     off += (size_t)NB * MSTRIDE * 4;
    int*    bcnt   = (int*)(w + off);     off += (size_t)NB * NCHK * 4;
    int*    fcnt   = (int*)(w + off);     off += (size_t)NB * 4;
    int*    fbflag = (int*)(w + off);     off += (size_t)NB * 4;
    float*  pSp    = (float*)(w + off);   off += (size_t)NBLK * 4;
    float*  pIl2   = (float*)(w + off);   off += (size_t)NB * NSQ * 4;
    float*  pOl    = (float*)(w + off);   off += (size_t)NB * NSQ * 4;
    int*    pNf2   = (int*)(w + off);     off += (size_t)NB * NSQ * 4;
    off = (off + 255) & ~(size_t)255;
    float4* A0      = (float4*)(w + off); off += (size_t)NB * NA * 16;
    float4* PK0     = (float4*)(w + off); off += (size_t)NB * NA * 16;
    unsigned long long* bestkey = (unsigned long long*)(w + off); off += (size_t)NB * NA * 8;
    float*  OC      = (float*)(w + off);  off += (size_t)NB * NA * 4;
    float*  PKO     = (float*)(w + off);  off += (size_t)NB * NA * 4;
    int*    PKA     = (int*)(w + off);    off += (size_t)NB * NA * 4;
    int*    cidx    = (int*)(w + off);    off += (size_t)NB * NA * 4;
    int*    n_match = (int*)(w + off);    off += (size_t)NB * NA * 4;
    int*    mg_min  = (int*)(w + off);    off += (size_t)NB * NA * 4;
    int*    mlist   = (int*)(w + off);    off += (size_t)NB * MCAP * 4;

    dim3 gA(NCHK, NB);   // 84 x 16

    k_decode<<<gA, 256, 0, stream>>>(reg0, obj0, reg1, obj1, reg2, obj2, labels,
                                     A0, OC, cidx, bcnt, pSp);
    k_pack<<<gA, 256, 0, stream>>>(A0, OC, cidx, bcnt, PK0, PKO, PKA, fcnt,
                                   n_match, mg_min, bestkey, mcount, fbflag);
    k_assign<<<dim3(NB * NG), 256, 0, stream>>>(labels, A0, OC, PK0, PKO, PKA, fcnt,
                                                n_match, mg_min, mlist, mcount,
                                                bestkey, fbflag);
    k_sparse<<<dim3(NSQ, NB), 256, 0, stream>>>(labels, obj0, obj1, obj2, A0, OC,
                                                n_match, mg_min, mlist, mcount,
                                                bestkey, fbflag, pIl2, pOl, pNf2);
    k_fin<<<1, 256, 0, stream>>>(pSp, pIl2, pOl, pNf2, labels, out);
}